// Round 1
// 3803.681 us; speedup vs baseline: 1.0208x; 1.0208x over previous
//
#include <hip/hip_runtime.h>
#include <hip/hip_bf16.h>
#include <math.h>

#define NL 4
#define KC 1024
#define FD 512
#define MT 32          // rows per block (was 16: halves per-row codebook L2 traffic + serial-phase instances)
#define BLK 512        // 8 waves: (rh,wc) = (wave>>2, wave&3) -> 2 row-halves x 4 col-groups
#define HBLK 256       // helper kernels keep their verified 256-thread shape
#define RS 516         // resid LDS row stride (+4 floats: 2-way banks, 16B aligned)
#define PPS 132        // pool row stride (floats): 128 entries + 4 pad so scanner float4 loads spread banks
#define NCAND 6

typedef __attribute__((ext_vector_type(8))) short short8;   // 8 bf16 (4 VGPRs)
typedef __attribute__((ext_vector_type(4))) float f32x4;    // MFMA acc

__device__ __forceinline__ short bf16c(float x) {
  __hip_bfloat16 h = __float2bfloat16(x);
  return *reinterpret_cast<short*>(&h);
}

// ---- numpy pairwise-sum emulation over 128 squares (verified bit-exact R4) --
__device__ __forceinline__ float np_chunk_partial(const float* p, int l16) {
  float pm[8];
#pragma unroll
  for (int m = 0; m < 8; m++) {
    float v = p[m * 16 + l16];
    pm[m] = __fmul_rn(v, v);
  }
  float a = __fadd_rn(__fadd_rn(pm[0], pm[1]), __fadd_rn(pm[2], pm[3]));
  float b = __fadd_rn(__fadd_rn(pm[4], pm[5]), __fadd_rn(pm[6], pm[7]));
  return __fadd_rn(a, b);
}

// ---- c2[l][k] = np.sum(cb*cb, axis=1), np-pairwise fp32 (verified R4) ------
__global__ __launch_bounds__(HBLK) void c2_kernel(const float* __restrict__ cb,
                                                  float* __restrict__ c2) {
  int wid  = (blockIdx.x * HBLK + threadIdx.x) >> 6;
  int lane = threadIdx.x & 63;
  if (wid >= NL * KC) return;
  const float* row = cb + (size_t)wid * FD;
  int chunk = lane >> 4, l16 = lane & 15;
  float part = np_chunk_partial(row + chunk * 128, l16);
  part = __fadd_rn(part, __shfl_xor(part, 8));
  part = __fadd_rn(part, __shfl_xor(part, 4));
  part = __fadd_rn(part, __shfl_xor(part, 2));
  part = __fadd_rn(part, __shfl_xor(part, 1));
  float s1 = __fadd_rn(part, __shfl_xor(part, 16));
  float s  = __fadd_rn(s1, __shfl_xor(s1, 32));
  if (lane == 0) c2[wid] = s;
}

// ---- swizzle cb fp32 -> bf16 in B-fragment order ----------------------------
// frag w = ((l*16 + c)*64 + T): element [lane][j] = cb[l][T*16+(lane&15)]
//                                                    [c*32+(lane>>4)*8+j]
__global__ __launch_bounds__(HBLK) void swz_kernel(const float* __restrict__ cb,
                                                   short* __restrict__ cbw) {
  int g = blockIdx.x * HBLK + threadIdx.x;
  int w = g >> 6, lane = g & 63;
  if (w >= NL * 16 * 64) return;
  int l = w >> 10, c = (w >> 6) & 15, T = w & 63;
  int kidx = T * 16 + (lane & 15);
  int f0   = c * 32 + ((lane >> 4) << 3);
  const float* src = cb + (((size_t)l * KC + kidx) * FD + f0);
  short8 v;
#pragma unroll
  for (int j = 0; j < 8; j++) v[j] = bf16c(src[j]);
  *(short8*)(cbw + (size_t)w * 512 + lane * 8) = v;
}

// insertion into sorted top-NCAND list; strict total order on (d, k) so the
// resulting set/order is scan-order independent (all k distinct).
#define INS(dval, kval) do {                                              \
    float _d = (dval); int _k = (kval);                                   \
    _Pragma("unroll")                                                     \
    for (int _j = 0; _j < NCAND; _j++) {                                  \
      bool _b = (_d < cd[_j]) || (_d == cd[_j] && _k < ck[_j]);           \
      if (_b) { float _td = cd[_j]; cd[_j] = _d; _d = _td;                \
                int   _tk = ck[_j]; ck[_j] = _k; _k = _tk; }              \
    }                                                                     \
  } while (0)

// ---- fused 4-layer RQ: bf16-MFMA filter -> top-6 -> bit-exact fp32 rescore --
__global__ __launch_bounds__(BLK, 2) void rq_kernel(
    const float* __restrict__ data, const float* __restrict__ cb,
    const float* __restrict__ c2g, const short* __restrict__ cbw,
    float* __restrict__ codes_out, float* __restrict__ recon_out, int N) {
  __shared__ float resid[MT * RS];        // 66 KB exact fp32 residual
  __shared__ float pool_d[MT * PPS];      // 16.5 KB filter pool scores
  __shared__ int   pool_k[MT * PPS];      // 16.5 KB filter pool indices
  __shared__ float mrg_d[MT * 24];        // 3 KB
  __shared__ int   mrg_k[MT * 24];        // 3 KB
  __shared__ float sh_part[MT * 64];      // 8 KB x2 lane partials
  __shared__ float sh_x2[MT];
  __shared__ float sc_d[MT * NCAND];
  __shared__ int   sc_k[MT * NCAND];
  __shared__ int   cand_k[MT * NCAND];
  __shared__ int   hist_k[NL * MT];

  const int t    = threadIdx.x;
  const int n0   = blockIdx.x * MT;
  if (n0 >= N) return;
  const int wv    = t >> 6;
  const int lane  = t & 63;
  const int l15   = lane & 15;
  const int lq    = lane >> 4;
  const int rh    = wv >> 2;     // row half: rows rh*16..+16
  const int wc    = wv & 3;      // col group: cols wc*256..+256
  const int rbase = rh << 4;

  // residual := data (rows clamped; clamped rows never write outputs)
#pragma unroll
  for (int q = 0; q < 8; q++) {
    int id = t + BLK * q;                  // 4096 float4 = 32 rows x 128
    int m = id >> 7, c4 = id & 127;
    int mg = n0 + m; if (mg > N - 1) mg = N - 1;
    *(float4*)&resid[m * RS + c4 * 4] =
        *(const float4*)&data[(size_t)mg * FD + c4 * 4];
  }
  __syncthreads();

  float4 rec[8];   // recon accumulated in registers, np order ((q0+q1)+q2)+q3

  for (int l = 0; l < NL; l++) {
    const float* cbl = cb + (size_t)l * KC * FD;

    // ---- exact x2[row], np-pairwise (verified R4); 512 thr cover 32 rows ----
    {
      int row = t >> 4, j16 = t & 15;
#pragma unroll
      for (int c = 0; c < 4; c++)
        sh_part[(row * 4 + c) * 16 + j16] =
            np_chunk_partial(&resid[row * RS + c * 128], j16);
    }
    __syncthreads();
    if (t < MT) {
      const float* P = &sh_part[t * 64];
      float b[4];
#pragma unroll
      for (int c = 0; c < 4; c++) {
        float u[8];
#pragma unroll
        for (int j2 = 0; j2 < 8; j2++)
          u[j2] = __fadd_rn(P[c * 16 + j2], P[c * 16 + j2 + 8]);
        float v[4];
#pragma unroll
        for (int j2 = 0; j2 < 4; j2++) v[j2] = __fadd_rn(u[j2], u[j2 + 4]);
        b[c] = __fadd_rn(__fadd_rn(v[0], v[2]), __fadd_rn(v[1], v[3]));
      }
      sh_x2[t] = __fadd_rn(__fadd_rn(b[0], b[1]), __fadd_rn(b[2], b[3]));
    }
    __syncthreads();

    // ---- bf16 MFMA filter GEMM: wave (rh,wc) covers rows rbase..+16,
    //      cols wc*256..+255. rh=0/1 waves read identical B -> L1 reuse. ----
    f32x4 acc[16];
#pragma unroll
    for (int tt = 0; tt < 16; tt++) acc[tt] = (f32x4)0.f;

    float c2f[16];
#pragma unroll
    for (int tt = 0; tt < 16; tt++)
      c2f[tt] = c2g[l * KC + wc * 256 + tt * 16 + l15];

    for (int ch = 0; ch < 16; ch++) {
      // A-frag: A[m=lane&15][k=(lane>>4)*8+j] from exact residual, cvt bf16
      float4 alo = *(const float4*)&resid[(rbase + l15) * RS + ch * 32 + lq * 8];
      float4 ahi = *(const float4*)&resid[(rbase + l15) * RS + ch * 32 + lq * 8 + 4];
      short8 av;
      av[0] = bf16c(alo.x); av[1] = bf16c(alo.y);
      av[2] = bf16c(alo.z); av[3] = bf16c(alo.w);
      av[4] = bf16c(ahi.x); av[5] = bf16c(ahi.y);
      av[6] = bf16c(ahi.z); av[7] = bf16c(ahi.w);
      const short8* bp =
          (const short8*)(cbw + (((size_t)l * 16 + ch) * 64 + wc * 16) * 512);
#pragma unroll
      for (int tt = 0; tt < 16; tt++) {
        short8 bv = bp[tt * 64 + lane];   // coalesced 1KB per wave
        acc[tt] = __builtin_amdgcn_mfma_f32_16x16x32_bf16(av, bv, acc[tt],
                                                          0, 0, 0);
      }
    }

    // ---- filter scores -> per-lane top-2 -> pool[row][128] ----
    // C layout (m89): col=lane&15, row=(lane>>4)*4+reg
#pragma unroll
    for (int g = 0; g < 4; g++) {
      float b1 = INFINITY, b2 = INFINITY; int k1 = 0x7fffffff, k2 = 0x7fffffff;
#pragma unroll
      for (int tt = 0; tt < 16; tt++) {
        float s = c2f[tt] - 2.0f * acc[tt][g];
        int k = wc * 256 + tt * 16 + l15;
        if (s < b1) { b2 = b1; k2 = k1; b1 = s; k1 = k; }
        else if (s < b2) { b2 = s; k2 = k; }
      }
      int r = rbase + lq * 4 + g;
      int base = r * PPS + wc * 32 + l15 * 2;
      pool_d[base] = b1; pool_k[base] = k1;
      pool_d[base + 1] = b2; pool_k[base + 1] = k2;
    }
    __syncthreads();

    // ---- stage A: 4 scanners/row x 32 rows = 128 threads; batched float4
    //      register loads (kills the old scalar-LDS latency chain), then
    //      pure-VALU top-6 insertion over 32 entries ----
    if (t < 4 * MT) {
      int r = t >> 2, seg = t & 3;
      const float4* pd4 = (const float4*)&pool_d[r * PPS + seg * 32];
      const int4*   pk4 = (const int4*)  &pool_k[r * PPS + seg * 32];
      float4 dv[8]; int4 kv[8];
#pragma unroll
      for (int e = 0; e < 8; e++) { dv[e] = pd4[e]; kv[e] = pk4[e]; }
      float cd[NCAND]; int ck[NCAND];
#pragma unroll
      for (int j = 0; j < NCAND; j++) { cd[j] = INFINITY; ck[j] = 0x7fffffff; }
#pragma unroll
      for (int e = 0; e < 8; e++) {
        INS(dv[e].x, kv[e].x); INS(dv[e].y, kv[e].y);
        INS(dv[e].z, kv[e].z); INS(dv[e].w, kv[e].w);
      }
#pragma unroll
      for (int j = 0; j < NCAND; j++) {
        mrg_d[r * 24 + seg * NCAND + j] = cd[j];
        mrg_k[r * 24 + seg * NCAND + j] = ck[j];
      }
    }
    __syncthreads();

    // ---- stage B: merge 24 -> top-6 candidates (batched loads) ----
    if (t < MT) {
      const float4* md4 = (const float4*)&mrg_d[t * 24];   // t*96B: 16B aligned
      const int4*   mk4 = (const int4*)  &mrg_k[t * 24];
      float4 dv[6]; int4 kv[6];
#pragma unroll
      for (int e = 0; e < 6; e++) { dv[e] = md4[e]; kv[e] = mk4[e]; }
      float cd[NCAND]; int ck[NCAND];
#pragma unroll
      for (int j = 0; j < NCAND; j++) { cd[j] = INFINITY; ck[j] = 0x7fffffff; }
#pragma unroll
      for (int e = 0; e < 6; e++) {
        INS(dv[e].x, kv[e].x); INS(dv[e].y, kv[e].y);
        INS(dv[e].z, kv[e].z); INS(dv[e].w, kv[e].w);
      }
#pragma unroll
      for (int j = 0; j < NCAND; j++) cand_k[t * NCAND + j] = ck[j];
    }
    __syncthreads();

    // ---- bit-exact fp32 rescore of candidates (verified recipe from R4):
    // s = fl(fl(x2 + c2[k]) - fl(2*dot)), dot = sequential single FMA chain
    if (t < MT * NCAND) {
      int r = t / NCAND, c = t - r * NCAND;
      int k = cand_k[r * NCAND + c];
      const float* cw = cbl + (size_t)k * FD;
      float sum = 0.f;
#pragma unroll 8
      for (int i = 0; i < 128; i++) {
        float4 rv = *(const float4*)&resid[r * RS + i * 4];
        float4 qv = *(const float4*)&cw[i * 4];
        sum = __fmaf_rn(rv.x, qv.x, sum);
        sum = __fmaf_rn(rv.y, qv.y, sum);
        sum = __fmaf_rn(rv.z, qv.z, sum);
        sum = __fmaf_rn(rv.w, qv.w, sum);
      }
      float c2e = c2g[l * KC + k];
      sc_d[r * NCAND + c] = __fsub_rn(__fadd_rn(sh_x2[r], c2e),
                                      __fmul_rn(2.0f, sum));
      sc_k[r * NCAND + c] = k;
    }
    __syncthreads();

    // ---- exact argmin among candidates, ties -> lowest k ----
    if (t < MT) {
      float bd = INFINITY; int bk = 0x7fffffff;
#pragma unroll
      for (int c = 0; c < NCAND; c++) {
        float d = sc_d[t * NCAND + c];
        int   k = sc_k[t * NCAND + c];
        if (d < bd || (d == bd && k < bk)) { bd = d; bk = k; }
      }
      hist_k[l * MT + t] = bk;
      if (n0 + t < N) codes_out[(size_t)(n0 + t) * NL + l] = (float)bk;
    }
    __syncthreads();

    // ---- fused: recon accumulate (np order) + exact fp32 residual update ----
    // same (t,q)->(m,c4) mapping every layer, so rec[q] accumulates
    // ((q0+q1)+q2)+q3 per element exactly; l=0 assigns (avoids 0+(-0) hazard).
#pragma unroll
    for (int q = 0; q < 8; q++) {
      int id = t + BLK * q;
      int m = id >> 7, c4 = id & 127;
      int bk2 = hist_k[l * MT + m];
      float4 qv = *(const float4*)&cbl[(size_t)bk2 * FD + c4 * 4];
      if (l == 0) {
        rec[q] = qv;
      } else {
        rec[q].x = __fadd_rn(rec[q].x, qv.x);
        rec[q].y = __fadd_rn(rec[q].y, qv.y);
        rec[q].z = __fadd_rn(rec[q].z, qv.z);
        rec[q].w = __fadd_rn(rec[q].w, qv.w);
      }
      if (l < NL - 1) {
        float4 rv = *(float4*)&resid[m * RS + c4 * 4];
        rv.x = __fsub_rn(rv.x, qv.x); rv.y = __fsub_rn(rv.y, qv.y);
        rv.z = __fsub_rn(rv.z, qv.z); rv.w = __fsub_rn(rv.w, qv.w);
        *(float4*)&resid[m * RS + c4 * 4] = rv;
      }
    }
    if (l < NL - 1) __syncthreads();
  }

  // ---- recon writeback from registers ----
#pragma unroll
  for (int q = 0; q < 8; q++) {
    int id = t + BLK * q;
    int m = id >> 7, c4 = id & 127;
    int mg = n0 + m;
    if (mg < N)
      *(float4*)&recon_out[(size_t)mg * FD + c4 * 4] = rec[q];
  }
}

extern "C" void kernel_launch(void* const* d_in, const int* in_sizes, int n_in,
                              void* d_out, int out_size, void* d_ws, size_t ws_size,
                              hipStream_t stream) {
  const float* data = (const float*)d_in[0];     // [N,512] fp32
  const float* cb   = (const float*)d_in[1];     // [4,1024,512] fp32
  int N = in_sizes[0] / FD;

  float* c2  = (float*)d_ws;                         // 16 KB
  short* cbw = (short*)((char*)d_ws + 16384);        // 4 MB bf16 swizzled
  float* codes_out = (float*)d_out;
  float* recon_out = codes_out + (size_t)N * NL;

  c2_kernel<<<(NL * KC + 3) / 4, HBLK, 0, stream>>>(cb, c2);
  swz_kernel<<<(NL * 16 * 64) / 4, HBLK, 0, stream>>>(cb, cbw);
  int nblocks = (N + MT - 1) / MT;
  rq_kernel<<<nblocks, BLK, 0, stream>>>(data, cb, c2, cbw, codes_out,
                                         recon_out, N);
}